// Round 21
// baseline (60.912 us; speedup 1.0000x reference)
//
#include <hip/hip_runtime.h>
#include <hip/hip_fp16.h>

// vol:  [B=8, D=64, H=128, W=128, C=2] f32
// flow: [B, D, H, W, 3] f32 (displacements)
// out:  [B, D, H, W, C] f32
//
// R21 = R20 (one-barrier 16-slot fp16 window, 8-row h-tiles, 4 vox/thread,
// pk-combine) + non-temporal hints on the two single-use streams:
//  - flow loads (101 MB, read once)  -> __builtin_nontemporal_load
//  - out stores (65 MB, write once)  -> __builtin_nontemporal_store
//  Keeps L2/L3 capacity for vol (re-read ~2.2x across halo-sharing blocks);
//  vol staging loads stay cached. Everything else identical to R20.

typedef float f32x4 __attribute__((ext_vector_type(4)));
typedef f32x4 __attribute__((aligned(8))) f32x4a;
typedef float f32x2 __attribute__((ext_vector_type(2)));

#define ROWU   130                 // uints per row (128 data + 2 pad)
#define SROWS  16                  // h-rows per plane-slot
#define SLOTU  (SROWS * ROWU)      // 2080 uints
#define NSLOT  16

__device__ __forceinline__ void sample_store(
    const float* __restrict__ vb, const uint* lds_u,
    float f0, float f1, float f2,
    int d, int h, int w, int dbase, int hbase,
    float* __restrict__ out, size_t vox)
{
    float cd = fminf(fmaxf((float)d + f0, 0.0f), 63.0f);
    float ch = fminf(fmaxf((float)h + f1, 0.0f), 127.0f);
    float cw = fminf(fmaxf((float)w + f2, 0.0f), 127.0f);
    int ld = (int)cd; ld = (ld > 62) ? 62 : ld;
    int lh = (int)ch; lh = (lh > 126) ? 126 : lh;
    int lw = (int)cw; lw = (lw > 126) ? 126 : lw;
    const float wd = cd - (float)ld;
    const float wh = ch - (float)lh;
    const float ww = cw - (float)lw;
    const int i_d = ld - dbase;   // LDS path: <= 10 (ld+1 in readable window)
    const int i_h = lh - hbase;   // LDS path: <= 14 (lh+1 row in slot)

    float ox, oy;
    if (__builtin_expect(((unsigned)i_d <= 10u) & ((unsigned)i_h <= 14u), 1)) {
        const int m0 = ld & 15;            // slot = plane mod 16
        const int m1 = (ld + 1) & 15;
        const int e0 = m0 * SLOTU + i_h * ROWU + lw;
        const int e1 = m1 * SLOTU + i_h * ROWU + lw;
        const uint uA0 = lds_u[e0],        uA1 = lds_u[e0 + 1];        // read2
        const uint uB0 = lds_u[e0 + ROWU], uB1 = lds_u[e0 + ROWU + 1]; // read2
        const uint uC0 = lds_u[e1],        uC1 = lds_u[e1 + 1];        // read2
        const uint uD0 = lds_u[e1 + ROWU], uD1 = lds_u[e1 + ROWU + 1]; // read2

        const __half2 cA0 = *(const __half2*)&uA0, cA1 = *(const __half2*)&uA1;
        const __half2 cB0 = *(const __half2*)&uB0, cB1 = *(const __half2*)&uB1;
        const __half2 cC0 = *(const __half2*)&uC0, cC1 = *(const __half2*)&uC1;
        const __half2 cD0 = *(const __half2*)&uD0, cD1 = *(const __half2*)&uD1;

        const __half2 ww2 = __float2half2_rn(ww);
        const __half2 wh2 = __float2half2_rn(wh);
        const __half2 wd2 = __float2half2_rn(wd);

        const __half2 a   = __hfma2(ww2, __hsub2(cA1, cA0), cA0);  // (ld  ,lh  )
        const __half2 bq  = __hfma2(ww2, __hsub2(cB1, cB0), cB0);  // (ld  ,lh+1)
        const __half2 c   = __hfma2(ww2, __hsub2(cC1, cC0), cC0);  // (ld+1,lh  )
        const __half2 dq  = __hfma2(ww2, __hsub2(cD1, cD0), cD0);  // (ld+1,lh+1)
        const __half2 ab  = __hfma2(wh2, __hsub2(bq, a), a);
        const __half2 cd2 = __hfma2(wh2, __hsub2(dq, c), c);
        const __half2 r   = __hfma2(wd2, __hsub2(cd2, ab), ab);
        ox = __low2float(r);
        oy = __high2float(r);
    } else {
        // exact f32 fallback (rare)
        const int o = (ld << 15) + (lh << 8) + (lw << 1);
        const f32x4 a00 = *(const f32x4a*)(vb + o);
        const f32x4 a01 = *(const f32x4a*)(vb + o + 256);
        const f32x4 a10 = *(const f32x4a*)(vb + o + 32768);
        const f32x4 a11 = *(const f32x4a*)(vb + o + 33024);
        const float xa = a00.x + ww * (a00.z - a00.x);
        const float ya = a00.y + ww * (a00.w - a00.y);
        const float xb = a01.x + ww * (a01.z - a01.x);
        const float yb = a01.y + ww * (a01.w - a01.y);
        const float xc = a10.x + ww * (a10.z - a10.x);
        const float yc = a10.y + ww * (a10.w - a10.y);
        const float xd = a11.x + ww * (a11.z - a11.x);
        const float yd = a11.y + ww * (a11.w - a11.y);
        const float xab = xa + wh * (xb - xa), yab = ya + wh * (yb - ya);
        const float xcd = xc + wh * (xd - xc), ycd = yc + wh * (yd - yc);
        ox = xab + wd * (xcd - xab);
        oy = yab + wd * (ycd - yab);
    }

    f32x2 r2; r2.x = ox; r2.y = oy;
    __builtin_nontemporal_store(r2, (f32x2*)(out + vox * 2));  // nt: no L2 alloc
}

// non-temporal 3-float flow read
#define NTF3(P, A, B, C)                          \
    A = __builtin_nontemporal_load((P));          \
    B = __builtin_nontemporal_load((P) + 1);      \
    C = __builtin_nontemporal_load((P) + 2);

__global__ __launch_bounds__(1024, 4) void st_nt_kernel(
    const float* __restrict__ vol,
    const float* __restrict__ flow,
    float* __restrict__ out)
{
    __shared__ uint lds_u[NSLOT * SLOTU];   // 133,120 B (1 block/CU)

    const int t   = threadIdx.x;
    const int bid = blockIdx.x;             // b*32 + htile*2 + dhalf
    const int dhalf  = bid & 1;
    const int h0     = ((bid >> 1) & 15) << 3;   // 8-row h-tile
    const int b      = bid >> 5;
    const int hbase  = h0 - 4;
    const int dstart = dhalf << 5;               // 0 or 32

    const float* vb = vol + ((size_t)b << 21);

    const int lane = t & 63;
    const int wid  = t >> 6;                // 0..15
    const int dr   = wid >> 2;              // 0..3
    const int hA   = h0 + ((wid & 3) << 1); // wave's rows: hA, hA+1

    // ---- initial stage: planes dstart-4..dstart+7, 16 rows each ----
#pragma unroll
    for (int j = 0; j < 12; ++j) {
        const int c   = t + (j << 10);      // 0..12287
        const int s   = c >> 6, q = c & 63; // row-slot, 16B chunk
        const int i_d = s >> 4, i_h = s & 15;
        const int p   = dstart - 4 + i_d;
        const int gd  = min(max(p, 0), 63);
        const int gh  = min(max(hbase + i_h, 0), 127);
        const f32x4 v = *(const f32x4*)(vb + ((((size_t)gd << 7) + gh) << 8) + (q << 2));
        const int sl  = p & 15;             // two's-complement & = mod 16
        const __half2 ha = __floats2half2_rn(v.x, v.y);
        const __half2 hb = __floats2half2_rn(v.z, v.w);
        uint2 pk; pk.x = *(const uint*)&ha; pk.y = *(const uint*)&hb;
        *(uint2*)&lds_u[sl * SLOTU + i_h * ROWU + (q << 1)] = pk;
    }

    // prologue flow: 4 voxels (rows hA, hA+1; w = lane, lane+64)
    float cA0,cA1,cA2, cB0,cB1,cB2, cC0,cC1,cC2, cD0,cD1,cD2;
    {
        const int d = dstart + dr;
        const size_t rbA = ((((size_t)((b << 6) | d) << 7) | hA) << 7);
        NTF3(flow + (rbA + lane) * 3,        cA0, cA1, cA2)
        NTF3(flow + (rbA + lane + 64) * 3,   cB0, cB1, cB2)
        NTF3(flow + (rbA + 128 + lane) * 3,  cC0, cC1, cC2)
        NTF3(flow + (rbA + 192 + lane) * 3,  cD0, cD1, cD2)
    }
    __syncthreads();

    for (int dt = 0; dt < 8; ++dt) {
        const int d0    = dstart + (dt << 2);
        const int dbase = d0 - 4;
        const int d     = d0 + dr;
        const size_t rbA  = ((((size_t)((b << 6) | d) << 7) | hA) << 7);
        const size_t voxA = rbA + lane;

        // ---- prefetch next-iter staging (4 f32x4) + flow (12 f32) ----
        f32x4 s0, s1, s2, s3;
        int   le0 = 0, le1 = 0, le2 = 0, le3 = 0;
        float nA0,nA1,nA2, nB0,nB1,nB2, nC0,nC1,nC2, nD0,nD1,nD2;
        if (dt < 7) {
#define ISSUE_ST(K, VV, EE)                                                      \
            {                                                                    \
                const int c = t + ((K) << 10);                                   \
                const int row = c >> 6, q = c & 63;                              \
                const int i_d4 = row >> 4, i_h = row & 15;                       \
                const int p  = d0 + 8 + i_d4;      /* new planes d0+8..d0+11 */  \
                const int gd = (p > 63) ? 63 : p;                                \
                const int gh = min(max(hbase + i_h, 0), 127);                    \
                VV = *(const f32x4*)(vb + ((((size_t)gd << 7) + gh) << 8) + (q << 2)); \
                EE = (p & 15) * SLOTU + i_h * ROWU + (q << 1);                   \
            }
            ISSUE_ST(0, s0, le0) ISSUE_ST(1, s1, le1)
            ISSUE_ST(2, s2, le2) ISSUE_ST(3, s3, le3)
#undef ISSUE_ST
            const int dn = d + 4;
            const size_t rbn = ((((size_t)((b << 6) | dn) << 7) | hA) << 7);
            NTF3(flow + (rbn + lane) * 3,       nA0, nA1, nA2)
            NTF3(flow + (rbn + lane + 64) * 3,  nB0, nB1, nB2)
            NTF3(flow + (rbn + 128 + lane) * 3, nC0, nC1, nC2)
            NTF3(flow + (rbn + 192 + lane) * 3, nD0, nD1, nD2)
            __builtin_amdgcn_sched_barrier(0);   // pin prefetch above gather
        }

        // ---- gather current tile (4 voxels/thread) ----
        sample_store(vb, lds_u, cA0, cA1, cA2, d, hA,     lane,      dbase, hbase, out, voxA);
        sample_store(vb, lds_u, cB0, cB1, cB2, d, hA,     lane + 64, dbase, hbase, out, voxA + 64);
        sample_store(vb, lds_u, cC0, cC1, cC2, d, hA + 1, lane,      dbase, hbase, out, voxA + 128);
        sample_store(vb, lds_u, cD0, cD1, cD2, d, hA + 1, lane + 64, dbase, hbase, out, voxA + 192);

        // ---- write new planes (slots disjoint from this iter's reads) ----
        if (dt < 7) {
#define WRPK(VV, EE)                                                             \
            {                                                                    \
                const __half2 ha = __floats2half2_rn(VV.x, VV.y);                \
                const __half2 hb = __floats2half2_rn(VV.z, VV.w);                \
                uint2 pk; pk.x = *(const uint*)&ha; pk.y = *(const uint*)&hb;    \
                *(uint2*)&lds_u[EE] = pk;                                        \
            }
            WRPK(s0, le0) WRPK(s1, le1) WRPK(s2, le2) WRPK(s3, le3)
#undef WRPK
            __syncthreads();   // single barrier: publish planes d0+8..d0+11
            cA0 = nA0; cA1 = nA1; cA2 = nA2;
            cB0 = nB0; cB1 = nB1; cB2 = nB2;
            cC0 = nC0; cC1 = nC1; cC2 = nC2;
            cD0 = nD0; cD1 = nD1; cD2 = nD2;
        }
    }
}

extern "C" void kernel_launch(void* const* d_in, const int* in_sizes, int n_in,
                              void* d_out, int out_size, void* d_ws, size_t ws_size,
                              hipStream_t stream) {
    const float* vol  = (const float*)d_in[0];
    const float* flow = (const float*)d_in[1];
    float* out = (float*)d_out;

    // 8 batches x 16 h-tiles x 2 d-halves = 256 persistent blocks (1 per CU)
    hipLaunchKernelGGL(st_nt_kernel, dim3(256), dim3(1024), 0, stream,
                       vol, flow, out);
}

// Round 22
// 58.129 us; speedup vs baseline: 1.0479x; 1.0479x over previous
//
#include <hip/hip_runtime.h>
#include <hip/hip_fp16.h>

// vol:  [B=8, D=64, H=128, W=128, C=2] f32
// flow: [B, D, H, W, 3] f32 (displacements)
// out:  [B, D, H, W, C] f32
//
// R22 = R20 (one-barrier 16-slot fp16 window, 8-row h-tiles, 4 vox/thread,
// pk-combine, reg-prefetch pipeline) + NT on OUT STORES ONLY.
//  - out stores (65 MB, written once, never re-read): nontemporal -> no
//    L2 write-allocate pressure on the vol working set.
//  - flow loads: normal cached (R21's NT loads risked L1 re-fetch: each
//    64B flow line is shared by ~5 lanes across the 12 scalar loads).
//  - staging loads issued before flow loads (oldest-first vmcnt drain).
// Geometry: 256 blocks = 8b x 16 h-tiles(8 rows) x 2 d-halves; 1 block/CU;
// 8 iters x 4096 voxels; LDS = 16 slots x 16 rows x 130 uints = 133,120 B.

typedef float f32x4 __attribute__((ext_vector_type(4)));
typedef f32x4 __attribute__((aligned(8))) f32x4a;
typedef float f32x2 __attribute__((ext_vector_type(2)));

#define ROWU   130                 // uints per row (128 data + 2 pad)
#define SROWS  16                  // h-rows per plane-slot
#define SLOTU  (SROWS * ROWU)      // 2080 uints
#define NSLOT  16

__device__ __forceinline__ void sample_store(
    const float* __restrict__ vb, const uint* lds_u,
    float f0, float f1, float f2,
    int d, int h, int w, int dbase, int hbase,
    float* __restrict__ out, size_t vox)
{
    float cd = fminf(fmaxf((float)d + f0, 0.0f), 63.0f);
    float ch = fminf(fmaxf((float)h + f1, 0.0f), 127.0f);
    float cw = fminf(fmaxf((float)w + f2, 0.0f), 127.0f);
    int ld = (int)cd; ld = (ld > 62) ? 62 : ld;
    int lh = (int)ch; lh = (lh > 126) ? 126 : lh;
    int lw = (int)cw; lw = (lw > 126) ? 126 : lw;
    const float wd = cd - (float)ld;
    const float wh = ch - (float)lh;
    const float ww = cw - (float)lw;
    const int i_d = ld - dbase;   // LDS path: <= 10 (ld+1 in readable window)
    const int i_h = lh - hbase;   // LDS path: <= 14 (lh+1 row in slot)

    float ox, oy;
    if (__builtin_expect(((unsigned)i_d <= 10u) & ((unsigned)i_h <= 14u), 1)) {
        const int m0 = ld & 15;            // slot = plane mod 16
        const int m1 = (ld + 1) & 15;
        const int e0 = m0 * SLOTU + i_h * ROWU + lw;
        const int e1 = m1 * SLOTU + i_h * ROWU + lw;
        const uint uA0 = lds_u[e0],        uA1 = lds_u[e0 + 1];        // read2
        const uint uB0 = lds_u[e0 + ROWU], uB1 = lds_u[e0 + ROWU + 1]; // read2
        const uint uC0 = lds_u[e1],        uC1 = lds_u[e1 + 1];        // read2
        const uint uD0 = lds_u[e1 + ROWU], uD1 = lds_u[e1 + ROWU + 1]; // read2

        const __half2 cA0 = *(const __half2*)&uA0, cA1 = *(const __half2*)&uA1;
        const __half2 cB0 = *(const __half2*)&uB0, cB1 = *(const __half2*)&uB1;
        const __half2 cC0 = *(const __half2*)&uC0, cC1 = *(const __half2*)&uC1;
        const __half2 cD0 = *(const __half2*)&uD0, cD1 = *(const __half2*)&uD1;

        const __half2 ww2 = __float2half2_rn(ww);
        const __half2 wh2 = __float2half2_rn(wh);
        const __half2 wd2 = __float2half2_rn(wd);

        const __half2 a   = __hfma2(ww2, __hsub2(cA1, cA0), cA0);  // (ld  ,lh  )
        const __half2 bq  = __hfma2(ww2, __hsub2(cB1, cB0), cB0);  // (ld  ,lh+1)
        const __half2 c   = __hfma2(ww2, __hsub2(cC1, cC0), cC0);  // (ld+1,lh  )
        const __half2 dq  = __hfma2(ww2, __hsub2(cD1, cD0), cD0);  // (ld+1,lh+1)
        const __half2 ab  = __hfma2(wh2, __hsub2(bq, a), a);
        const __half2 cd2 = __hfma2(wh2, __hsub2(dq, c), c);
        const __half2 r   = __hfma2(wd2, __hsub2(cd2, ab), ab);
        ox = __low2float(r);
        oy = __high2float(r);
    } else {
        // exact f32 fallback (rare, P ~ 1e-4)
        const int o = (ld << 15) + (lh << 8) + (lw << 1);
        const f32x4 a00 = *(const f32x4a*)(vb + o);
        const f32x4 a01 = *(const f32x4a*)(vb + o + 256);
        const f32x4 a10 = *(const f32x4a*)(vb + o + 32768);
        const f32x4 a11 = *(const f32x4a*)(vb + o + 33024);
        const float xa = a00.x + ww * (a00.z - a00.x);
        const float ya = a00.y + ww * (a00.w - a00.y);
        const float xb = a01.x + ww * (a01.z - a01.x);
        const float yb = a01.y + ww * (a01.w - a01.y);
        const float xc = a10.x + ww * (a10.z - a10.x);
        const float yc = a10.y + ww * (a10.w - a10.y);
        const float xd = a11.x + ww * (a11.z - a11.x);
        const float yd = a11.y + ww * (a11.w - a11.y);
        const float xab = xa + wh * (xb - xa), yab = ya + wh * (yb - ya);
        const float xcd = xc + wh * (xd - xc), ycd = yc + wh * (yd - yc);
        ox = xab + wd * (xcd - xab);
        oy = yab + wd * (ycd - yab);
    }

    f32x2 r2; r2.x = ox; r2.y = oy;
    __builtin_nontemporal_store(r2, (f32x2*)(out + vox * 2));  // nt store only
}

__global__ __launch_bounds__(1024, 4) void st_nt2_kernel(
    const float* __restrict__ vol,
    const float* __restrict__ flow,
    float* __restrict__ out)
{
    __shared__ uint lds_u[NSLOT * SLOTU];   // 133,120 B (1 block/CU)

    const int t   = threadIdx.x;
    const int bid = blockIdx.x;             // b*32 + htile*2 + dhalf
    const int dhalf  = bid & 1;
    const int h0     = ((bid >> 1) & 15) << 3;   // 8-row h-tile
    const int b      = bid >> 5;
    const int hbase  = h0 - 4;
    const int dstart = dhalf << 5;               // 0 or 32

    const float* vb = vol + ((size_t)b << 21);

    const int lane = t & 63;
    const int wid  = t >> 6;                // 0..15
    const int dr   = wid >> 2;              // 0..3
    const int hA   = h0 + ((wid & 3) << 1); // wave's rows: hA, hA+1

    // ---- initial stage: planes dstart-4..dstart+7, 16 rows each ----
#pragma unroll
    for (int j = 0; j < 12; ++j) {
        const int c   = t + (j << 10);      // 0..12287
        const int s   = c >> 6, q = c & 63; // row-slot, 16B chunk
        const int i_d = s >> 4, i_h = s & 15;
        const int p   = dstart - 4 + i_d;
        const int gd  = min(max(p, 0), 63);
        const int gh  = min(max(hbase + i_h, 0), 127);
        const f32x4 v = *(const f32x4*)(vb + ((((size_t)gd << 7) + gh) << 8) + (q << 2));
        const int sl  = p & 15;             // two's-complement & = mod 16
        const __half2 ha = __floats2half2_rn(v.x, v.y);
        const __half2 hb = __floats2half2_rn(v.z, v.w);
        uint2 pk; pk.x = *(const uint*)&ha; pk.y = *(const uint*)&hb;
        *(uint2*)&lds_u[sl * SLOTU + i_h * ROWU + (q << 1)] = pk;
    }

    // prologue flow: 4 voxels (rows hA, hA+1; w = lane, lane+64)
    float cA0,cA1,cA2, cB0,cB1,cB2, cC0,cC1,cC2, cD0,cD1,cD2;
    {
        const int d = dstart + dr;
        const size_t rbA = ((((size_t)((b << 6) | d) << 7) | hA) << 7);
        const float* fA = flow + (rbA + lane) * 3;
        cA0 = fA[0]; cA1 = fA[1]; cA2 = fA[2];
        const float* fB = flow + (rbA + lane + 64) * 3;
        cB0 = fB[0]; cB1 = fB[1]; cB2 = fB[2];
        const float* fC = flow + (rbA + 128 + lane) * 3;
        cC0 = fC[0]; cC1 = fC[1]; cC2 = fC[2];
        const float* fD = flow + (rbA + 192 + lane) * 3;
        cD0 = fD[0]; cD1 = fD[1]; cD2 = fD[2];
    }
    __syncthreads();

    for (int dt = 0; dt < 8; ++dt) {
        const int d0    = dstart + (dt << 2);
        const int dbase = d0 - 4;
        const int d     = d0 + dr;
        const size_t rbA  = ((((size_t)((b << 6) | d) << 7) | hA) << 7);
        const size_t voxA = rbA + lane;

        // ---- prefetch next-iter staging (4 f32x4, issued FIRST) + flow ----
        f32x4 s0, s1, s2, s3;
        int   le0 = 0, le1 = 0, le2 = 0, le3 = 0;
        float nA0,nA1,nA2, nB0,nB1,nB2, nC0,nC1,nC2, nD0,nD1,nD2;
        if (dt < 7) {
#define ISSUE_ST(K, VV, EE)                                                      \
            {                                                                    \
                const int c = t + ((K) << 10);                                   \
                const int row = c >> 6, q = c & 63;                              \
                const int i_d4 = row >> 4, i_h = row & 15;                       \
                const int p  = d0 + 8 + i_d4;      /* new planes d0+8..d0+11 */  \
                const int gd = (p > 63) ? 63 : p;                                \
                const int gh = min(max(hbase + i_h, 0), 127);                    \
                VV = *(const f32x4*)(vb + ((((size_t)gd << 7) + gh) << 8) + (q << 2)); \
                EE = (p & 15) * SLOTU + i_h * ROWU + (q << 1);                   \
            }
            ISSUE_ST(0, s0, le0) ISSUE_ST(1, s1, le1)
            ISSUE_ST(2, s2, le2) ISSUE_ST(3, s3, le3)
#undef ISSUE_ST
            const int dn = d + 4;
            const size_t rbn = ((((size_t)((b << 6) | dn) << 7) | hA) << 7);
            const float* fA = flow + (rbn + lane) * 3;
            nA0 = fA[0]; nA1 = fA[1]; nA2 = fA[2];
            const float* fB = flow + (rbn + lane + 64) * 3;
            nB0 = fB[0]; nB1 = fB[1]; nB2 = fB[2];
            const float* fC = flow + (rbn + 128 + lane) * 3;
            nC0 = fC[0]; nC1 = fC[1]; nC2 = fC[2];
            const float* fD = flow + (rbn + 192 + lane) * 3;
            nD0 = fD[0]; nD1 = fD[1]; nD2 = fD[2];
            __builtin_amdgcn_sched_barrier(0);   // pin prefetch above gather
        }

        // ---- gather current tile (4 voxels/thread) ----
        sample_store(vb, lds_u, cA0, cA1, cA2, d, hA,     lane,      dbase, hbase, out, voxA);
        sample_store(vb, lds_u, cB0, cB1, cB2, d, hA,     lane + 64, dbase, hbase, out, voxA + 64);
        sample_store(vb, lds_u, cC0, cC1, cC2, d, hA + 1, lane,      dbase, hbase, out, voxA + 128);
        sample_store(vb, lds_u, cD0, cD1, cD2, d, hA + 1, lane + 64, dbase, hbase, out, voxA + 192);

        // ---- write new planes (slots disjoint from this iter's reads) ----
        if (dt < 7) {
#define WRPK(VV, EE)                                                             \
            {                                                                    \
                const __half2 ha = __floats2half2_rn(VV.x, VV.y);                \
                const __half2 hb = __floats2half2_rn(VV.z, VV.w);                \
                uint2 pk; pk.x = *(const uint*)&ha; pk.y = *(const uint*)&hb;    \
                *(uint2*)&lds_u[EE] = pk;                                        \
            }
            WRPK(s0, le0) WRPK(s1, le1) WRPK(s2, le2) WRPK(s3, le3)
#undef WRPK
            __syncthreads();   // single barrier: publish planes d0+8..d0+11
            cA0 = nA0; cA1 = nA1; cA2 = nA2;
            cB0 = nB0; cB1 = nB1; cB2 = nB2;
            cC0 = nC0; cC1 = nC1; cC2 = nC2;
            cD0 = nD0; cD1 = nD1; cD2 = nD2;
        }
    }
}

extern "C" void kernel_launch(void* const* d_in, const int* in_sizes, int n_in,
                              void* d_out, int out_size, void* d_ws, size_t ws_size,
                              hipStream_t stream) {
    const float* vol  = (const float*)d_in[0];
    const float* flow = (const float*)d_in[1];
    float* out = (float*)d_out;

    // 8 batches x 16 h-tiles x 2 d-halves = 256 persistent blocks (1 per CU)
    hipLaunchKernelGGL(st_nt2_kernel, dim3(256), dim3(1024), 0, stream,
                       vol, flow, out);
}

// Round 23
// 57.398 us; speedup vs baseline: 1.0612x; 1.0127x over previous
//
#include <hip/hip_runtime.h>
#include <hip/hip_fp16.h>

// vol:  [B=8, D=64, H=128, W=128, C=2] f32
// flow: [B, D, H, W, 3] f32 (displacements)
// out:  [B, D, H, W, C] f32
//
// R23 = R22 (one-barrier 16-slot fp16 window, 8-row h-tiles, 4 vox/thread,
// pk-combine, NT out-stores) with the per-iter __syncthreads() replaced by
//   s_waitcnt lgkmcnt(0) ; sched_barrier(0) ; s_barrier
// -> the barrier no longer drains vmcnt(0), so out-store acks and staging
// loads keep flying across the iteration boundary (LDS ordering is fully
// covered by lgkmcnt(0) + barrier; register data deps on prefetched values
// get compiler-inserted vmcnt(N) waits at their uses).

typedef float f32x4 __attribute__((ext_vector_type(4)));
typedef f32x4 __attribute__((aligned(8))) f32x4a;
typedef float f32x2 __attribute__((ext_vector_type(2)));

#define ROWU   130                 // uints per row (128 data + 2 pad)
#define SROWS  16                  // h-rows per plane-slot
#define SLOTU  (SROWS * ROWU)      // 2080 uints
#define NSLOT  16

// LDS-only barrier: order ds ops across the workgroup WITHOUT draining vmcnt
__device__ __forceinline__ void lds_barrier() {
    asm volatile("s_waitcnt lgkmcnt(0)" ::: "memory");
    __builtin_amdgcn_sched_barrier(0);
    __builtin_amdgcn_s_barrier();
}

__device__ __forceinline__ void sample_store(
    const float* __restrict__ vb, const uint* lds_u,
    float f0, float f1, float f2,
    int d, int h, int w, int dbase, int hbase,
    float* __restrict__ out, size_t vox)
{
    float cd = fminf(fmaxf((float)d + f0, 0.0f), 63.0f);
    float ch = fminf(fmaxf((float)h + f1, 0.0f), 127.0f);
    float cw = fminf(fmaxf((float)w + f2, 0.0f), 127.0f);
    int ld = (int)cd; ld = (ld > 62) ? 62 : ld;
    int lh = (int)ch; lh = (lh > 126) ? 126 : lh;
    int lw = (int)cw; lw = (lw > 126) ? 126 : lw;
    const float wd = cd - (float)ld;
    const float wh = ch - (float)lh;
    const float ww = cw - (float)lw;
    const int i_d = ld - dbase;   // LDS path: <= 10 (ld+1 in readable window)
    const int i_h = lh - hbase;   // LDS path: <= 14 (lh+1 row in slot)

    float ox, oy;
    if (__builtin_expect(((unsigned)i_d <= 10u) & ((unsigned)i_h <= 14u), 1)) {
        const int m0 = ld & 15;            // slot = plane mod 16
        const int m1 = (ld + 1) & 15;
        const int e0 = m0 * SLOTU + i_h * ROWU + lw;
        const int e1 = m1 * SLOTU + i_h * ROWU + lw;
        const uint uA0 = lds_u[e0],        uA1 = lds_u[e0 + 1];        // read2
        const uint uB0 = lds_u[e0 + ROWU], uB1 = lds_u[e0 + ROWU + 1]; // read2
        const uint uC0 = lds_u[e1],        uC1 = lds_u[e1 + 1];        // read2
        const uint uD0 = lds_u[e1 + ROWU], uD1 = lds_u[e1 + ROWU + 1]; // read2

        const __half2 cA0 = *(const __half2*)&uA0, cA1 = *(const __half2*)&uA1;
        const __half2 cB0 = *(const __half2*)&uB0, cB1 = *(const __half2*)&uB1;
        const __half2 cC0 = *(const __half2*)&uC0, cC1 = *(const __half2*)&uC1;
        const __half2 cD0 = *(const __half2*)&uD0, cD1 = *(const __half2*)&uD1;

        const __half2 ww2 = __float2half2_rn(ww);
        const __half2 wh2 = __float2half2_rn(wh);
        const __half2 wd2 = __float2half2_rn(wd);

        const __half2 a   = __hfma2(ww2, __hsub2(cA1, cA0), cA0);  // (ld  ,lh  )
        const __half2 bq  = __hfma2(ww2, __hsub2(cB1, cB0), cB0);  // (ld  ,lh+1)
        const __half2 c   = __hfma2(ww2, __hsub2(cC1, cC0), cC0);  // (ld+1,lh  )
        const __half2 dq  = __hfma2(ww2, __hsub2(cD1, cD0), cD0);  // (ld+1,lh+1)
        const __half2 ab  = __hfma2(wh2, __hsub2(bq, a), a);
        const __half2 cd2 = __hfma2(wh2, __hsub2(dq, c), c);
        const __half2 r   = __hfma2(wd2, __hsub2(cd2, ab), ab);
        ox = __low2float(r);
        oy = __high2float(r);
    } else {
        // exact f32 fallback (rare, P ~ 1e-4)
        const int o = (ld << 15) + (lh << 8) + (lw << 1);
        const f32x4 a00 = *(const f32x4a*)(vb + o);
        const f32x4 a01 = *(const f32x4a*)(vb + o + 256);
        const f32x4 a10 = *(const f32x4a*)(vb + o + 32768);
        const f32x4 a11 = *(const f32x4a*)(vb + o + 33024);
        const float xa = a00.x + ww * (a00.z - a00.x);
        const float ya = a00.y + ww * (a00.w - a00.y);
        const float xb = a01.x + ww * (a01.z - a01.x);
        const float yb = a01.y + ww * (a01.w - a01.y);
        const float xc = a10.x + ww * (a10.z - a10.x);
        const float yc = a10.y + ww * (a10.w - a10.y);
        const float xd = a11.x + ww * (a11.z - a11.x);
        const float yd = a11.y + ww * (a11.w - a11.y);
        const float xab = xa + wh * (xb - xa), yab = ya + wh * (yb - ya);
        const float xcd = xc + wh * (xd - xc), ycd = yc + wh * (yd - yc);
        ox = xab + wd * (xcd - xab);
        oy = yab + wd * (ycd - yab);
    }

    f32x2 r2; r2.x = ox; r2.y = oy;
    __builtin_nontemporal_store(r2, (f32x2*)(out + vox * 2));  // nt store
}

__global__ __launch_bounds__(1024, 4) void st_ldsbar_kernel(
    const float* __restrict__ vol,
    const float* __restrict__ flow,
    float* __restrict__ out)
{
    __shared__ uint lds_u[NSLOT * SLOTU];   // 133,120 B (1 block/CU)

    const int t   = threadIdx.x;
    const int bid = blockIdx.x;             // b*32 + htile*2 + dhalf
    const int dhalf  = bid & 1;
    const int h0     = ((bid >> 1) & 15) << 3;   // 8-row h-tile
    const int b      = bid >> 5;
    const int hbase  = h0 - 4;
    const int dstart = dhalf << 5;               // 0 or 32

    const float* vb = vol + ((size_t)b << 21);

    const int lane = t & 63;
    const int wid  = t >> 6;                // 0..15
    const int dr   = wid >> 2;              // 0..3
    const int hA   = h0 + ((wid & 3) << 1); // wave's rows: hA, hA+1

    // ---- initial stage: planes dstart-4..dstart+7, 16 rows each ----
#pragma unroll
    for (int j = 0; j < 12; ++j) {
        const int c   = t + (j << 10);      // 0..12287
        const int s   = c >> 6, q = c & 63; // row-slot, 16B chunk
        const int i_d = s >> 4, i_h = s & 15;
        const int p   = dstart - 4 + i_d;
        const int gd  = min(max(p, 0), 63);
        const int gh  = min(max(hbase + i_h, 0), 127);
        const f32x4 v = *(const f32x4*)(vb + ((((size_t)gd << 7) + gh) << 8) + (q << 2));
        const int sl  = p & 15;             // two's-complement & = mod 16
        const __half2 ha = __floats2half2_rn(v.x, v.y);
        const __half2 hb = __floats2half2_rn(v.z, v.w);
        uint2 pk; pk.x = *(const uint*)&ha; pk.y = *(const uint*)&hb;
        *(uint2*)&lds_u[sl * SLOTU + i_h * ROWU + (q << 1)] = pk;
    }

    // prologue flow: 4 voxels (rows hA, hA+1; w = lane, lane+64)
    float cA0,cA1,cA2, cB0,cB1,cB2, cC0,cC1,cC2, cD0,cD1,cD2;
    {
        const int d = dstart + dr;
        const size_t rbA = ((((size_t)((b << 6) | d) << 7) | hA) << 7);
        const float* fA = flow + (rbA + lane) * 3;
        cA0 = fA[0]; cA1 = fA[1]; cA2 = fA[2];
        const float* fB = flow + (rbA + lane + 64) * 3;
        cB0 = fB[0]; cB1 = fB[1]; cB2 = fB[2];
        const float* fC = flow + (rbA + 128 + lane) * 3;
        cC0 = fC[0]; cC1 = fC[1]; cC2 = fC[2];
        const float* fD = flow + (rbA + 192 + lane) * 3;
        cD0 = fD[0]; cD1 = fD[1]; cD2 = fD[2];
    }
    __syncthreads();   // full barrier here: initial staging must be complete

    for (int dt = 0; dt < 8; ++dt) {
        const int d0    = dstart + (dt << 2);
        const int dbase = d0 - 4;
        const int d     = d0 + dr;
        const size_t rbA  = ((((size_t)((b << 6) | d) << 7) | hA) << 7);
        const size_t voxA = rbA + lane;

        // ---- prefetch next-iter staging (4 f32x4, issued FIRST) + flow ----
        f32x4 s0, s1, s2, s3;
        int   le0 = 0, le1 = 0, le2 = 0, le3 = 0;
        float nA0,nA1,nA2, nB0,nB1,nB2, nC0,nC1,nC2, nD0,nD1,nD2;
        if (dt < 7) {
#define ISSUE_ST(K, VV, EE)                                                      \
            {                                                                    \
                const int c = t + ((K) << 10);                                   \
                const int row = c >> 6, q = c & 63;                              \
                const int i_d4 = row >> 4, i_h = row & 15;                       \
                const int p  = d0 + 8 + i_d4;      /* new planes d0+8..d0+11 */  \
                const int gd = (p > 63) ? 63 : p;                                \
                const int gh = min(max(hbase + i_h, 0), 127);                    \
                VV = *(const f32x4*)(vb + ((((size_t)gd << 7) + gh) << 8) + (q << 2)); \
                EE = (p & 15) * SLOTU + i_h * ROWU + (q << 1);                   \
            }
            ISSUE_ST(0, s0, le0) ISSUE_ST(1, s1, le1)
            ISSUE_ST(2, s2, le2) ISSUE_ST(3, s3, le3)
#undef ISSUE_ST
            const int dn = d + 4;
            const size_t rbn = ((((size_t)((b << 6) | dn) << 7) | hA) << 7);
            const float* fA = flow + (rbn + lane) * 3;
            nA0 = fA[0]; nA1 = fA[1]; nA2 = fA[2];
            const float* fB = flow + (rbn + lane + 64) * 3;
            nB0 = fB[0]; nB1 = fB[1]; nB2 = fB[2];
            const float* fC = flow + (rbn + 128 + lane) * 3;
            nC0 = fC[0]; nC1 = fC[1]; nC2 = fC[2];
            const float* fD = flow + (rbn + 192 + lane) * 3;
            nD0 = fD[0]; nD1 = fD[1]; nD2 = fD[2];
            __builtin_amdgcn_sched_barrier(0);   // pin prefetch above gather
        }

        // ---- gather current tile (4 voxels/thread) ----
        sample_store(vb, lds_u, cA0, cA1, cA2, d, hA,     lane,      dbase, hbase, out, voxA);
        sample_store(vb, lds_u, cB0, cB1, cB2, d, hA,     lane + 64, dbase, hbase, out, voxA + 64);
        sample_store(vb, lds_u, cC0, cC1, cC2, d, hA + 1, lane,      dbase, hbase, out, voxA + 128);
        sample_store(vb, lds_u, cD0, cD1, cD2, d, hA + 1, lane + 64, dbase, hbase, out, voxA + 192);

        // ---- write new planes (slots disjoint from this iter's reads) ----
        if (dt < 7) {
#define WRPK(VV, EE)                                                             \
            {                                                                    \
                const __half2 ha = __floats2half2_rn(VV.x, VV.y);                \
                const __half2 hb = __floats2half2_rn(VV.z, VV.w);                \
                uint2 pk; pk.x = *(const uint*)&ha; pk.y = *(const uint*)&hb;    \
                *(uint2*)&lds_u[EE] = pk;                                        \
            }
            WRPK(s0, le0) WRPK(s1, le1) WRPK(s2, le2) WRPK(s3, le3)
#undef WRPK
            // LDS-only barrier: publish planes d0+8..d0+11 WITHOUT draining
            // vmcnt (out-store acks + any loads keep flying).
            lds_barrier();
            cA0 = nA0; cA1 = nA1; cA2 = nA2;
            cB0 = nB0; cB1 = nB1; cB2 = nB2;
            cC0 = nC0; cC1 = nC1; cC2 = nC2;
            cD0 = nD0; cD1 = nD1; cD2 = nD2;
        }
    }
}

extern "C" void kernel_launch(void* const* d_in, const int* in_sizes, int n_in,
                              void* d_out, int out_size, void* d_ws, size_t ws_size,
                              hipStream_t stream) {
    const float* vol  = (const float*)d_in[0];
    const float* flow = (const float*)d_in[1];
    float* out = (float*)d_out;

    // 8 batches x 16 h-tiles x 2 d-halves = 256 persistent blocks (1 per CU)
    hipLaunchKernelGGL(st_ldsbar_kernel, dim3(256), dim3(1024), 0, stream,
                       vol, flow, out);
}